// Round 1
// baseline (362.742 us; speedup 1.0000x reference)
//
#include <hip/hip_runtime.h>

// 3D neighborhood attention (KS=3) + softmax + expected-offset contraction.
// q,k: (1,64,64,64,96) fp32 ; rpb: (6,3,3,3) fp32 ; out: (1,18,64,64,64) fp32
//
// Block = one (h,w) column; 384 threads = 64 t-positions x 6 heads (tid = t*6+n).
// Per thread: q fragment (16 floats, pre-scaled), 27 logits in registers,
// two-pass softmax, attn @ offset-vectors collapses to +/- adds.

#define DH 64
#define DW 64
#define DT 64
#define DC 96
#define NH 6
#define HD 16

__global__ __launch_bounds__(384) void natten3d_kernel(
    const float* __restrict__ q,
    const float* __restrict__ k,
    const float* __restrict__ rpb,
    float* __restrict__ out)
{
    // ---- bijective XCD swizzle: 4096 blocks, 8 XCDs, 512 contiguous per XCD
    int bid = blockIdx.x;
    int nb  = (bid & 7) * 512 + (bid >> 3);
    int h = nb >> 6;          // nb / 64
    int w = nb & 63;          // nb % 64

    int tid = threadIdx.x;
    int t = tid / NH;
    int n = tid - t * NH;

    // ---- load q fragment, pre-scaled by hd^-0.5 = 0.25
    const float* qp = q + ((size_t)((h * DW + w) * DT + t)) * DC + n * HD;
    float qv[HD];
    #pragma unroll
    for (int i = 0; i < HD / 4; ++i) {
        float4 v4 = *reinterpret_cast<const float4*>(qp + 4 * i);
        qv[4 * i + 0] = v4.x * 0.25f;
        qv[4 * i + 1] = v4.y * 0.25f;
        qv[4 * i + 2] = v4.z * 0.25f;
        qv[4 * i + 3] = v4.w * 0.25f;
    }

    // ---- 27 logits: dot(q, k_neighbor) + rpb ; OOB neighbor -> dot = 0 (zero-pad)
    float logits[27];
    #pragma unroll
    for (int di = 0; di < 3; ++di) {
        int hh = h + di - 1;
        bool hok = (unsigned)hh < DH;
        #pragma unroll
        for (int dj = 0; dj < 3; ++dj) {
            int ww = w + dj - 1;
            bool hwok = hok && ((unsigned)ww < DW);
            const float* kbase = k + ((size_t)(hh * DW + ww) * DT) * DC + n * HD;
            #pragma unroll
            for (int dt = 0; dt < 3; ++dt) {
                int tt = t + dt - 1;
                int o = di * 9 + dj * 3 + dt;
                float s = 0.f;
                if (hwok && (unsigned)tt < DT) {
                    const float* kp = kbase + (size_t)tt * DC;
                    #pragma unroll
                    for (int i = 0; i < HD / 4; ++i) {
                        float4 kv = *reinterpret_cast<const float4*>(kp + 4 * i);
                        s = fmaf(qv[4 * i + 0], kv.x, s);
                        s = fmaf(qv[4 * i + 1], kv.y, s);
                        s = fmaf(qv[4 * i + 2], kv.z, s);
                        s = fmaf(qv[4 * i + 3], kv.w, s);
                    }
                }
                logits[o] = s + rpb[n * 27 + o];
            }
        }
    }

    // ---- softmax over 27 + expected offset (offsets in {-1,0,1} -> add/sub)
    float m = logits[0];
    #pragma unroll
    for (int o = 1; o < 27; ++o) m = fmaxf(m, logits[o]);

    float l = 0.f, a0 = 0.f, a1 = 0.f, a2 = 0.f;
    #pragma unroll
    for (int o = 0; o < 27; ++o) {
        float p = __expf(logits[o] - m);
        l += p;
        const int di = o / 9, dj = (o / 3) % 3, dt = o % 3;
        a0 += p * (float)(di - 1);
        a1 += p * (float)(dj - 1);
        a2 += p * (float)(dt - 1);
    }
    float inv = 1.f / l;
    a0 *= inv; a1 *= inv; a2 *= inv;

    // out[(n*3+axis)][h][w][t], plane = 64^3
    size_t plane = (size_t)DH * DW * DT;
    size_t sp = (size_t)(h * DW + w) * DT + t;
    out[(size_t)(n * 3 + 0) * plane + sp] = a0;
    out[(size_t)(n * 3 + 1) * plane + sp] = a1;
    out[(size_t)(n * 3 + 2) * plane + sp] = a2;
}

extern "C" void kernel_launch(void* const* d_in, const int* in_sizes, int n_in,
                              void* d_out, int out_size, void* d_ws, size_t ws_size,
                              hipStream_t stream) {
    const float* q   = (const float*)d_in[0];
    const float* k   = (const float*)d_in[1];
    const float* rpb = (const float*)d_in[2];
    float* out = (float*)d_out;

    dim3 grid(DH * DW);   // 4096 blocks, one per (h,w)
    dim3 block(DT * NH);  // 384 threads = 64 t x 6 heads
    hipLaunchKernelGGL(natten3d_kernel, grid, block, 0, stream, q, k, rpb, out);
}